// Round 4
// baseline (2782.181 us; speedup 1.0000x reference)
//
#include <hip/hip_runtime.h>
#include <stdint.h>

// ---------- types ----------
typedef __bf16 bf16x8 __attribute__((ext_vector_type(8)));
typedef float  f32x4  __attribute__((ext_vector_type(4)));
typedef unsigned short ushortx8 __attribute__((ext_vector_type(8)));
typedef unsigned short ushortx4 __attribute__((ext_vector_type(4)));

#define DEVI __device__ __forceinline__

DEVI unsigned short f2bf(float f) {
  union { float f; unsigned int u; } v; v.f = f;
  unsigned int r = v.u + 0x7fffu + ((v.u >> 16) & 1u);
  return (unsigned short)(r >> 16);
}
DEVI float bf2f(unsigned short h) {
  union { unsigned int u; float f; } v; v.u = ((unsigned int)h) << 16;
  return v.f;
}

// async global->LDS, 16B per lane (counts on vmcnt, completes in issue order)
DEVI void gl_lds16(const unsigned short* g, unsigned short* l) {
  __builtin_amdgcn_global_load_lds(
      (__attribute__((address_space(1))) unsigned int*)g,
      (__attribute__((address_space(3))) unsigned int*)l,
      16, 0, 0);
}

// Counted waits (m201 snippet style). Plain builtin barriers elsewhere.
#define AWT_VM(N)   asm volatile("s_waitcnt vmcnt(" #N ")")
#define AWT_LGKM(N) asm volatile("s_waitcnt lgkmcnt(" #N ")")

DEVI void store_out(float* p, float v) { *p = v; }
DEVI void store_out(unsigned short* p, float v) { *p = f2bf(v); }

// ---------- GroupNorm stats: one block per (batch, group) ----------
__global__ __launch_bounds__(256) void gn_stats(const float* __restrict__ x,
                                                float* __restrict__ stats) {
  const int bg = blockIdx.x;
  const float* p = x + (size_t)bg * 65536;
  const int tid = threadIdx.x;
  float s = 0.f, ss = 0.f;
#pragma unroll 4
  for (int i = 0; i < 64; ++i) {
    float4 v = *(const float4*)(p + (((size_t)i * 256 + tid) << 2));
    s  += v.x + v.y + v.z + v.w;
    ss += v.x * v.x + v.y * v.y + v.z * v.z + v.w * v.w;
  }
  for (int off = 32; off; off >>= 1) { s += __shfl_xor(s, off); ss += __shfl_xor(ss, off); }
  __shared__ float rs[4], rss[4];
  const int lane = tid & 63, wave = tid >> 6;
  if (lane == 0) { rs[wave] = s; rss[wave] = ss; }
  __syncthreads();
  if (tid == 0) {
    float S1 = rs[0] + rs[1] + rs[2] + rs[3];
    float S2 = rss[0] + rss[1] + rss[2] + rss[3];
    float mean = S1 * (1.f / 65536.f);
    float var  = S2 * (1.f / 65536.f) - mean * mean;
    stats[bg * 2 + 0] = mean;
    stats[bg * 2 + 1] = rsqrtf(var + 1e-5f);
  }
}

// ---------- GN apply + transpose to token-major bf16 h_t[B,4096,512] ----------
__global__ __launch_bounds__(256) void gn_apply(const float* __restrict__ x,
                                                const float* __restrict__ stats,
                                                const float* __restrict__ gamma,
                                                const float* __restrict__ beta,
                                                unsigned short* __restrict__ h_t) {
  __shared__ alignas(16) unsigned short tile[64 * 136];
  const int tid = threadIdx.x;
  const int t0 = blockIdx.x * 64;
  const int c0 = blockIdx.y * 128;
  const int b  = blockIdx.z;
  const float* xb = x + ((size_t)b * 512 + c0) * 4096 + t0;
#pragma unroll
  for (int j = 0; j < 8; ++j) {
    int f = tid + j * 256;
    int r = f >> 4;
    int tc = (f & 15) << 2;
    float4 v = *(const float4*)(xb + (size_t)r * 4096 + tc);
    int ch = c0 + r;
    int g = ch >> 4;
    float mean = stats[((size_t)b * 32 + g) * 2 + 0];
    float rstd = stats[((size_t)b * 32 + g) * 2 + 1];
    float ga = gamma[ch] * rstd;
    float be = beta[ch] - mean * ga;
    tile[(tc + 0) * 136 + r] = f2bf(v.x * ga + be);
    tile[(tc + 1) * 136 + r] = f2bf(v.y * ga + be);
    tile[(tc + 2) * 136 + r] = f2bf(v.z * ga + be);
    tile[(tc + 3) * 136 + r] = f2bf(v.w * ga + be);
  }
  __syncthreads();
  unsigned short* hb = h_t + (size_t)b * 4096 * 512;
#pragma unroll
  for (int j = 0; j < 4; ++j) {
    int f = tid + j * 256;
    int tok = f >> 4;
    int cc = (f & 15) << 3;
    ushortx8 v = *(const ushortx8*)&tile[tok * 136 + cc];
    *(ushortx8*)(hb + (size_t)(t0 + tok) * 512 + c0 + cc) = v;
  }
}

// ---------- fp32 -> bf16 weight convert ----------
__global__ __launch_bounds__(256) void cvt_f32_bf16(const float* __restrict__ s,
                                                    unsigned short* __restrict__ d) {
  int i = (blockIdx.x * 256 + threadIdx.x) * 4;
  float4 v = *(const float4*)(s + i);
  ushortx4 o;
  o[0] = f2bf(v.x); o[1] = f2bf(v.y); o[2] = f2bf(v.z); o[3] = f2bf(v.w);
  *(ushortx4*)(d + i) = o;
}

// ---------- 256x256 8-phase NT-form MFMA GEMM, quadrant schedule ----------
// D[m,n] = alpha * sum_k A[m,k]*B[n,k] (+bias)(+resid)
// 512 threads = 8 waves (2M x 4N); per wave 128x64 output.
// Per phase: one quadrant's operand ds-read (8 A or 4 B b128), one 4-load
// STAGE on even phases, counted vmcnt(4) at P1/P2/P5/P6 (certify-before-
// barrier, read-after), s_barrier, lgkmcnt(0), 16 MFMA (quadrant x K=64),
// s_barrier. Never vmcnt(0) in the loop.
// Ledger: sB1<-B(t1)@P0 (read P3,P5), sA0<-A(t0+2)@P2 (read P6,P0'),
//         sB0<-B(t0+2)@P4 (read P7,P1'), sA1<-A(t1+2)@P6 (read P2',P4').
template <int BIAS_MODE, int RESID, int REMAP, typename OT>
__global__ __launch_bounds__(512, 2) void gemm_nt_256(
    const unsigned short* __restrict__ A, const unsigned short* __restrict__ B,
    OT* __restrict__ D, const float* __restrict__ bias,
    const float* __restrict__ resid, int M, int N, int K,
    long long sA, long long sB, long long sD, long long sR, float alpha) {
  __shared__ alignas(128) char sm[131072];
  char* const sA0 = sm;
  char* const sB0 = sm + 32768;
  char* const sA1 = sm + 65536;
  char* const sB1 = sm + 98304;

  const int tid = threadIdx.x;
  int bz, bn, bm;
  if (REMAP) {
    // XCD-affine: x (8) -> xcd & bn-inner, y (32) -> (bm, bn-chunk), z -> batch.
    // Per XCD per batch: B-footprint = 2 panels (512 KB) -> L2-resident.
    bz = blockIdx.z;
    bm = (int)blockIdx.y >> 1;
    bn = ((int)blockIdx.y & 1) * 8 + (int)blockIdx.x;
  } else {
    bz = blockIdx.x; bn = blockIdx.y; bm = blockIdx.z;
  }
  const unsigned short* Ab = A + (size_t)bz * sA + (size_t)bm * 256 * K;
  const unsigned short* Bb = B + (size_t)bz * sB + (size_t)bn * 256 * K;

  const int lane = tid & 63;
  const int ln = lane & 15, quad = lane >> 4;
  const int wave = tid >> 6;
  const int wm = wave >> 2, wn = wave & 3;

  // staging: thread t writes 16B; 4 chunks of 64 rows cover a 256x64 tile.
  // linear LDS dest; source k-slot pre-swizzled: (t&7) ^ (row&7)
  const int prow = tid >> 3;
  const unsigned ks = (unsigned)((tid & 7) ^ (prow & 7));
  const unsigned srcoff = (unsigned)prow * (unsigned)K + ks * 8u;  // elements
  const unsigned ldst = (unsigned)tid * 16u;                       // bytes

  // compute-read geometry (byte offsets, row stride 128B, swizzled k-slot)
  const int aro = (wm * 128 + ln) * 128;
  const int bro = (wn * 64 + ln) * 128;
  const int sl0 = ((quad ^ (ln & 7)) << 4);        // k-step 0
  const int sl1 = (((4 + quad) ^ (ln & 7)) << 4);  // k-step 1

  f32x4 acc[8][4] = {};
  bf16x8 aL0[8], aL1[8], aH[8], bL[4], bH[4];

#define STAGE4(G, SMp, ktv) do {                                                     \
    const unsigned short* _g = (G) + (unsigned)(ktv) * 64u + srcoff;                 \
    gl_lds16(_g,                   (unsigned short*)((SMp) + ldst));                 \
    gl_lds16(_g + (size_t)64 * K,  (unsigned short*)((SMp) + 8192 + ldst));          \
    gl_lds16(_g + (size_t)128 * K, (unsigned short*)((SMp) + 16384 + ldst));         \
    gl_lds16(_g + (size_t)192 * K, (unsigned short*)((SMp) + 24576 + ldst));         \
  } while (0)

// 8 reads: one A-quadrant (4 mf x 2 ksteps), dst[mi*2+ks]
#define RD_AQ(dst, SMp, MF0) do { _Pragma("unroll")                                  \
    for (int _mi = 0; _mi < 4; ++_mi) {                                              \
      dst[_mi * 2 + 0] = *(const bf16x8*)((SMp) + aro + (MF0 + _mi) * 2048 + sl0);   \
      dst[_mi * 2 + 1] = *(const bf16x8*)((SMp) + aro + (MF0 + _mi) * 2048 + sl1);   \
    } } while (0)
// 4 reads: one B-quadrant (2 nf x 2 ksteps), dst[ni*2+ks]
#define RD_BQ(dst, SMp, NF0) do { _Pragma("unroll")                                  \
    for (int _ni = 0; _ni < 2; ++_ni) {                                              \
      dst[_ni * 2 + 0] = *(const bf16x8*)((SMp) + bro + (NF0 + _ni) * 2048 + sl0);   \
      dst[_ni * 2 + 1] = *(const bf16x8*)((SMp) + bro + (NF0 + _ni) * 2048 + sl1);   \
    } } while (0)

// 16 MFMA: one C-quadrant x K=64 (2 chained ksteps per acc)
#define MMQ(AQ, BQ, MF0, NF0) do {                                                   \
    __builtin_amdgcn_s_setprio(1);                                                   \
    _Pragma("unroll")                                                                \
    for (int _mi = 0; _mi < 4; ++_mi) {                                              \
      _Pragma("unroll")                                                              \
      for (int _ni = 0; _ni < 2; ++_ni) {                                            \
        f32x4 _c = acc[(MF0) + _mi][(NF0) + _ni];                                    \
        _c = __builtin_amdgcn_mfma_f32_16x16x32_bf16(AQ[_mi * 2 + 0], BQ[_ni * 2 + 0], _c, 0, 0, 0); \
        _c = __builtin_amdgcn_mfma_f32_16x16x32_bf16(AQ[_mi * 2 + 1], BQ[_ni * 2 + 1], _c, 0, 0, 0); \
        acc[(MF0) + _mi][(NF0) + _ni] = _c;                                          \
      }                                                                              \
    }                                                                                \
    __builtin_amdgcn_s_setprio(0);                                                   \
  } while (0)

  const int KT = K >> 6;
  const int NI = K >> 7;

  // prologue: sA0<-A(0), sB0<-B(0), sA1<-A(1); certify first two; prime reads
  STAGE4(Ab, sA0, 0);
  STAGE4(Bb, sB0, 0);
  STAGE4(Ab, sA1, 1);
  AWT_VM(4);
  __builtin_amdgcn_s_barrier();
  RD_AQ(aL0, sA0, 0);   // Alo(t0)
  RD_BQ(bL,  sB0, 0);   // Blo(t0)

  for (int i = 0; i < NI; ++i) {
    const int t1 = 2 * i + 1;
    const int t2 = (2 * i + 2 < KT) ? 2 * i + 2 : KT - 1;  // clamped, dead on last iter
    const int t3 = (2 * i + 3 < KT) ? 2 * i + 3 : KT - 1;
    // P0: Q(lo,lo) t0
    RD_AQ(aH, sA0, 4);
    STAGE4(Bb, sB1, t1);
    __builtin_amdgcn_s_barrier(); AWT_LGKM(0);
    MMQ(aL0, bL, 0, 0);
    __builtin_amdgcn_s_barrier();
    // P1: Q(hi,lo) t0   [vm(4): certify sA1 <- A(t1)]
    RD_BQ(bH, sB0, 2);
    AWT_VM(4);
    __builtin_amdgcn_s_barrier(); AWT_LGKM(0);
    MMQ(aH, bL, 4, 0);
    __builtin_amdgcn_s_barrier();
    // P2: Q(hi,hi) t0   [vm(4): certify sB1 <- B(t1)]
    RD_AQ(aL1, sA1, 0);
    STAGE4(Ab, sA0, t2);
    AWT_VM(4);
    __builtin_amdgcn_s_barrier(); AWT_LGKM(0);
    MMQ(aH, bH, 4, 2);
    __builtin_amdgcn_s_barrier();
    // P3: Q(lo,hi) t0
    RD_BQ(bL, sB1, 0);
    __builtin_amdgcn_s_barrier(); AWT_LGKM(0);
    MMQ(aL0, bH, 0, 2);
    __builtin_amdgcn_s_barrier();
    // P4: Q(lo,lo) t1
    RD_AQ(aH, sA1, 4);
    STAGE4(Bb, sB0, t2);
    __builtin_amdgcn_s_barrier(); AWT_LGKM(0);
    MMQ(aL1, bL, 0, 0);
    __builtin_amdgcn_s_barrier();
    // P5: Q(hi,lo) t1   [vm(4): certify sA0 <- A(t2)]
    RD_BQ(bH, sB1, 2);
    AWT_VM(4);
    __builtin_amdgcn_s_barrier(); AWT_LGKM(0);
    MMQ(aH, bL, 4, 0);
    __builtin_amdgcn_s_barrier();
    // P6: Q(hi,hi) t1   [vm(4): certify sB0 <- B(t2)]
    RD_AQ(aL0, sA0, 0);
    STAGE4(Ab, sA1, t3);
    AWT_VM(4);
    __builtin_amdgcn_s_barrier(); AWT_LGKM(0);
    MMQ(aH, bH, 4, 2);
    __builtin_amdgcn_s_barrier();
    // P7: Q(lo,hi) t1
    RD_BQ(bL, sB0, 0);
    __builtin_amdgcn_s_barrier(); AWT_LGKM(0);
    MMQ(aL1, bH, 0, 2);
    __builtin_amdgcn_s_barrier();
  }
#undef STAGE4
#undef RD_AQ
#undef RD_BQ
#undef MMQ

  OT* Db = D + (size_t)bz * sD;
  const float* Rb = RESID ? (resid + (size_t)bz * sR) : nullptr;
#pragma unroll
  for (int mf = 0; mf < 8; ++mf) {
#pragma unroll
    for (int nf = 0; nf < 4; ++nf) {
#pragma unroll
      for (int r = 0; r < 4; ++r) {
        int row = bm * 256 + wm * 128 + mf * 16 + quad * 4 + r;
        int col = bn * 256 + wn * 64 + nf * 16 + ln;
        float v = acc[mf][nf][r] * alpha;
        if (BIAS_MODE == 1) v += bias[row];
        if (BIAS_MODE == 2) v += bias[col];
        size_t idx = (size_t)row * N + col;
        if (RESID) v += Rb[idx];
        store_out(&Db[idx], v);
      }
    }
  }
}

// ---------- row softmax over 4096 bf16, in place ----------
__global__ __launch_bounds__(256) void softmax_rows(unsigned short* __restrict__ S) {
  const int tid = threadIdx.x;
  unsigned short* p = S + (size_t)blockIdx.x * 4096 + tid * 16;
  ushortx8 u0 = *(const ushortx8*)p;
  ushortx8 u1 = *(const ushortx8*)(p + 8);
  float v[16];
#pragma unroll
  for (int i = 0; i < 8; ++i) { v[i] = bf2f(u0[i]); v[i + 8] = bf2f(u1[i]); }
  float m = v[0];
#pragma unroll
  for (int i = 1; i < 16; ++i) m = fmaxf(m, v[i]);
  for (int off = 32; off; off >>= 1) m = fmaxf(m, __shfl_xor(m, off));
  __shared__ float red[4];
  __shared__ float red2[4];
  const int lane = tid & 63, wave = tid >> 6;
  if (lane == 0) red[wave] = m;
  __syncthreads();
  m = fmaxf(fmaxf(red[0], red[1]), fmaxf(red[2], red[3]));
  float s = 0.f;
#pragma unroll
  for (int i = 0; i < 16; ++i) { v[i] = __expf(v[i] - m); s += v[i]; }
  for (int off = 32; off; off >>= 1) s += __shfl_xor(s, off);
  if (lane == 0) red2[wave] = s;
  __syncthreads();
  s = red2[0] + red2[1] + red2[2] + red2[3];
  float inv = 1.f / s;
#pragma unroll
  for (int i = 0; i < 8; ++i) { u0[i] = f2bf(v[i] * inv); u1[i] = f2bf(v[i + 8] * inv); }
  *(ushortx8*)p = u0;
  *(ushortx8*)(p + 8) = u1;
}

// ---------- host ----------
extern "C" void kernel_launch(void* const* d_in, const int* in_sizes, int n_in,
                              void* d_out, int out_size, void* d_ws, size_t ws_size,
                              hipStream_t stream) {
  const float* x   = (const float*)d_in[0];
  const float* gnw = (const float*)d_in[1];
  const float* gnb = (const float*)d_in[2];
  const float* wq  = (const float*)d_in[3];
  const float* bq  = (const float*)d_in[4];
  const float* wk  = (const float*)d_in[5];
  const float* bk  = (const float*)d_in[6];
  const float* wv  = (const float*)d_in[7];
  const float* bv  = (const float*)d_in[8];
  const float* wo  = (const float*)d_in[9];
  const float* bo  = (const float*)d_in[10];
  float* out = (float*)d_out;

  const size_t EB = 2097152;  // elems per batch in a [4096,512] buffer

  char* base = (char*)d_ws;
  unsigned short* h_t  = (unsigned short*)base;                    // 67,108,864 B
  unsigned short* wqb  = (unsigned short*)(base + 67108864);
  unsigned short* wkb  = wqb + 262144;
  unsigned short* wvb  = wkb + 262144;
  unsigned short* wob  = wvb + 262144;
  float*          stats = (float*)(base + 69206016);
  char*           dyn   = base + 69210112;
  size_t rem = ws_size > 69210112 ? ws_size - 69210112 : 0;

  // per-batch dynamic bytes: q+k+v (3 x 4 MiB) + S (32 MiB)
  int nb = 1;
  if      (rem >= (size_t)16 * 46137344) nb = 16;
  else if (rem >= (size_t)8  * 46137344) nb = 8;
  else if (rem >= (size_t)4  * 46137344) nb = 4;
  else if (rem >= (size_t)2  * 46137344) nb = 2;

  unsigned short* q  = (unsigned short*)dyn;
  unsigned short* kb = q  + (size_t)nb * EB;
  unsigned short* vb = kb + (size_t)nb * EB;
  unsigned short* Sb = (unsigned short*)(dyn + (size_t)nb * 3 * 4194304);
  unsigned short* attn = q;  // alias: q dead after S-GEMM within a chunk

  gn_stats<<<512, 256, 0, stream>>>(x, stats);
  gn_apply<<<dim3(64, 4, 16), 256, 0, stream>>>(x, stats, gnw, gnb, h_t);
  cvt_f32_bf16<<<256, 256, 0, stream>>>(wq, wqb);
  cvt_f32_bf16<<<256, 256, 0, stream>>>(wk, wkb);
  cvt_f32_bf16<<<256, 256, 0, stream>>>(wv, wvb);
  cvt_f32_bf16<<<256, 256, 0, stream>>>(wo, wob);

  const float sm_scale = 0.044194173824159216f;  // 1/sqrt(512)

  for (int b0 = 0; b0 < 16; b0 += nb) {
    const unsigned short* hc = h_t + (size_t)b0 * EB;
    // Q = h_t x wq^T  -> [tok, o] token-major   (grid: batch, bn, bm)
    gemm_nt_256<2, 0, 0, unsigned short><<<dim3(nb, 2, 16), 512, 0, stream>>>(
        hc, wqb, q, bq, nullptr, 4096, 512, 512, (long long)EB, 0, (long long)EB, 0, 1.f);
    gemm_nt_256<2, 0, 0, unsigned short><<<dim3(nb, 2, 16), 512, 0, stream>>>(
        hc, wkb, kb, bk, nullptr, 4096, 512, 512, (long long)EB, 0, (long long)EB, 0, 1.f);
    // V = wv x h_t^T -> [o, tok] channel-major
    gemm_nt_256<1, 0, 0, unsigned short><<<dim3(nb, 16, 2), 512, 0, stream>>>(
        wvb, hc, vb, bv, nullptr, 512, 4096, 512, 0, (long long)EB, (long long)EB, 0, 1.f);
    // S = Q K^T * scale  [4096, 4096]  (XCD-affine remap grid: 8 x 32 x nb)
    gemm_nt_256<0, 0, 1, unsigned short><<<dim3(8, 32, nb), 512, 0, stream>>>(
        q, kb, Sb, nullptr, nullptr, 4096, 4096, 512,
        (long long)EB, (long long)EB, 16777216LL, 0, sm_scale);
    softmax_rows<<<nb * 4096, 256, 0, stream>>>(Sb);
    // attn = P x V^T -> [tok, c] token-major (writes over q region)
    gemm_nt_256<0, 0, 0, unsigned short><<<dim3(nb, 2, 16), 512, 0, stream>>>(
        Sb, vb, attn, nullptr, nullptr, 4096, 512, 4096,
        16777216LL, (long long)EB, (long long)EB, 0, 1.f);
    // out = wo x attn^T + bo + x  [o, tok] fp32
    gemm_nt_256<1, 1, 0, float><<<dim3(nb, 16, 2), 512, 0, stream>>>(
        wob, attn, out + (size_t)b0 * EB, bo, x + (size_t)b0 * EB,
        512, 4096, 512, 0, (long long)EB, (long long)EB, (long long)EB, 1.f);
  }
}